// Round 1
// baseline (918.955 us; speedup 1.0000x reference)
//
#include <hip/hip_runtime.h>

// Bilinear scatter-add: out[H,W,D] += w_corner * feat[p,:] at 4 corners.
// N=500000, D=112, H=64, W=176. Direct-atomic baseline:
// thread = (point, channel); c = tid&127 (112 active of 128) so feature
// reads are coalesced and each wave's atomics hit consecutive addresses.

#define DCH 112

__global__ __launch_bounds__(256) void bilinear_scatter_kernel(
    const float* __restrict__ pos,     // [N,2] (x, y)
    const float* __restrict__ feat,    // [N,DCH]
    const int* __restrict__ hptr,      // scalar H
    const int* __restrict__ wptr,      // scalar W
    float* __restrict__ out,           // [H,W,DCH]
    int N)
{
    const int H = hptr[0];
    const int W = wptr[0];

    long long gid = (long long)blockIdx.x * blockDim.x + threadIdx.x;
    int p = (int)(gid >> 7);
    int c = (int)(gid & 127);
    if (p >= N || c >= DCH) return;

    const float x = pos[2 * p + 0];
    const float y = pos[2 * p + 1];

    const float x0f = floorf(x);
    const float y0f = floorf(y);
    const float wx = x - x0f;
    const float wy = y - y0f;
    const int x0 = (int)x0f;
    const int y0 = (int)y0f;
    const int x1 = x0 + 1;
    const int y1 = y0 + 1;

    const float f = feat[p * DCH + c];

    // corner (yi, xi, w) — match reference: zero weight if OOB, clamp index.
    {
        // (y0, x0)
        float w00 = (1.0f - wy) * (1.0f - wx);
        bool v = (y0 >= 0) & (y0 < H) & (x0 >= 0) & (x0 < W);
        float w = v ? w00 : 0.0f;
        if (w != 0.0f) {
            int yi = min(max(y0, 0), H - 1);
            int xi = min(max(x0, 0), W - 1);
            unsafeAtomicAdd(&out[(yi * W + xi) * DCH + c], w * f);
        }
    }
    {
        // (y0, x1)
        float w01 = (1.0f - wy) * wx;
        bool v = (y0 >= 0) & (y0 < H) & (x1 >= 0) & (x1 < W);
        float w = v ? w01 : 0.0f;
        if (w != 0.0f) {
            int yi = min(max(y0, 0), H - 1);
            int xi = min(max(x1, 0), W - 1);
            unsafeAtomicAdd(&out[(yi * W + xi) * DCH + c], w * f);
        }
    }
    {
        // (y1, x0)
        float w10 = wy * (1.0f - wx);
        bool v = (y1 >= 0) & (y1 < H) & (x0 >= 0) & (x0 < W);
        float w = v ? w10 : 0.0f;
        if (w != 0.0f) {
            int yi = min(max(y1, 0), H - 1);
            int xi = min(max(x0, 0), W - 1);
            unsafeAtomicAdd(&out[(yi * W + xi) * DCH + c], w * f);
        }
    }
    {
        // (y1, x1)
        float w11 = wy * wx;
        bool v = (y1 >= 0) & (y1 < H) & (x1 >= 0) & (x1 < W);
        float w = v ? w11 : 0.0f;
        if (w != 0.0f) {
            int yi = min(max(y1, 0), H - 1);
            int xi = min(max(x1, 0), W - 1);
            unsafeAtomicAdd(&out[(yi * W + xi) * DCH + c], w * f);
        }
    }
}

extern "C" void kernel_launch(void* const* d_in, const int* in_sizes, int n_in,
                              void* d_out, int out_size, void* d_ws, size_t ws_size,
                              hipStream_t stream) {
    const float* pos  = (const float*)d_in[0];
    const float* feat = (const float*)d_in[1];
    const int* hptr   = (const int*)d_in[2];
    const int* wptr   = (const int*)d_in[3];
    float* out        = (float*)d_out;

    const int N = in_sizes[0] / 2;

    // Harness poisons d_out with 0xAA before every launch — zero it.
    hipMemsetAsync(out, 0, (size_t)out_size * sizeof(float), stream);

    // 128 thread-slots per point (112 active channels), 256 threads/block.
    long long total = (long long)N * 128;
    int threads = 256;
    long long blocks = (total + threads - 1) / threads;
    bilinear_scatter_kernel<<<(dim3)(unsigned)blocks, threads, 0, stream>>>(
        pos, feat, hptr, wptr, out, N);
}

// Round 2
// 645.621 us; speedup vs baseline: 1.4234x; 1.4234x over previous
//
#include <hip/hip_runtime.h>

// Bilinear scatter-add via binning (scatter -> gather).
// N=500000, D=112, H=64, W=176, HW=11264 cells, ~178 entries/cell.
// R1 baseline (direct f32 atomics) was atomic-bound: 224M device atomics,
// WRITE_SIZE=875MB, 697us. This version: 2M int atomics for binning, then
// a gather pass with register accumulation and ONE store per output float.
//
// Workspace layout (ints/floats, 4B each):
//   cnt[HW] | cur[HW] | off[HW+1] | ep[4N] | ew[4N]   ~= 16.2 MB total.

#define CHUNK 128

__device__ __forceinline__ void corner_setup(float x, float y,
                                             int& x0, int& y0,
                                             float& wx, float& wy) {
    float x0f = floorf(x);
    float y0f = floorf(y);
    wx = x - x0f;
    wy = y - y0f;
    x0 = (int)x0f;
    y0 = (int)y0f;
}

__global__ __launch_bounds__(256) void count_kernel(
    const float* __restrict__ pos, const int* __restrict__ hptr,
    const int* __restrict__ wptr, int* __restrict__ cnt, int N)
{
    int p = blockIdx.x * blockDim.x + threadIdx.x;
    if (p >= N) return;
    const int H = hptr[0], W = wptr[0];
    int x0, y0; float wx, wy;
    corner_setup(pos[2 * p], pos[2 * p + 1], x0, y0, wx, wy);

    const int   xs[2] = { x0, x0 + 1 };
    const int   ys[2] = { y0, y0 + 1 };
    const float fx[2] = { 1.0f - wx, wx };
    const float fy[2] = { 1.0f - wy, wy };
#pragma unroll
    for (int iy = 0; iy < 2; ++iy)
#pragma unroll
        for (int ix = 0; ix < 2; ++ix) {
            float w = fy[iy] * fx[ix];
            int yi = ys[iy], xi = xs[ix];
            bool v = (yi >= 0) & (yi < H) & (xi >= 0) & (xi < W);
            if (v && w != 0.0f) atomicAdd(&cnt[yi * W + xi], 1);
        }
}

__global__ __launch_bounds__(1024) void scan_kernel(
    const int* __restrict__ cnt, int* __restrict__ off,
    int* __restrict__ cur, int HW, int K)
{
    __shared__ int part[1024];
    const int t = threadIdx.x;
    const int b = t * K;
    int s = 0;
    for (int i = 0; i < K; ++i) {
        int g = b + i;
        if (g < HW) s += cnt[g];
    }
    part[t] = s;
    __syncthreads();
    // Hillis-Steele inclusive scan over 1024 partials.
    for (int d = 1; d < 1024; d <<= 1) {
        int v = (t >= d) ? part[t - d] : 0;
        __syncthreads();
        part[t] += v;
        __syncthreads();
    }
    int run = (t > 0) ? part[t - 1] : 0;  // exclusive base for this thread
    for (int i = 0; i < K; ++i) {
        int g = b + i;
        if (g < HW) {
            off[g] = run;
            cur[g] = run;
            run += cnt[g];
        }
    }
    if (t == 1023) off[HW] = part[1023];
}

__global__ __launch_bounds__(256) void fill_kernel(
    const float* __restrict__ pos, const int* __restrict__ hptr,
    const int* __restrict__ wptr, int* __restrict__ cur,
    int* __restrict__ ep, float* __restrict__ ew, int N)
{
    int p = blockIdx.x * blockDim.x + threadIdx.x;
    if (p >= N) return;
    const int H = hptr[0], W = wptr[0];
    int x0, y0; float wx, wy;
    corner_setup(pos[2 * p], pos[2 * p + 1], x0, y0, wx, wy);

    const int   xs[2] = { x0, x0 + 1 };
    const int   ys[2] = { y0, y0 + 1 };
    const float fx[2] = { 1.0f - wx, wx };
    const float fy[2] = { 1.0f - wy, wy };
#pragma unroll
    for (int iy = 0; iy < 2; ++iy)
#pragma unroll
        for (int ix = 0; ix < 2; ++ix) {
            float w = fy[iy] * fx[ix];
            int yi = ys[iy], xi = xs[ix];
            bool v = (yi >= 0) & (yi < H) & (xi >= 0) & (xi < W);
            if (v && w != 0.0f) {
                int idx = atomicAdd(&cur[yi * W + xi], 1);
                ep[idx] = p;
                ew[idx] = w;
            }
        }
}

__global__ __launch_bounds__(128) void accumulate_kernel(
    const float* __restrict__ feat, const int* __restrict__ off,
    const int* __restrict__ ep, const float* __restrict__ ew,
    float* __restrict__ out, int D)
{
    const int cell = blockIdx.x;
    const int c = threadIdx.x;
    const int beg = off[cell];
    const int end = off[cell + 1];

    __shared__ int   sp[CHUNK];
    __shared__ float sw[CHUNK];

    float acc = 0.0f;
    for (int base = beg; base < end; base += CHUNK) {
        int n = min(CHUNK, end - base);
        if (threadIdx.x < n) {
            sp[threadIdx.x] = ep[base + threadIdx.x];
            sw[threadIdx.x] = ew[base + threadIdx.x];
        }
        __syncthreads();
        if (c < D) {
            for (int e = 0; e < n; ++e)
                acc = fmaf(sw[e], feat[sp[e] * D + c], acc);
        }
        __syncthreads();
    }
    // Every cell writes (out is poisoned each launch; empty cells -> 0).
    if (c < D) out[cell * D + c] = acc;
}

extern "C" void kernel_launch(void* const* d_in, const int* in_sizes, int n_in,
                              void* d_out, int out_size, void* d_ws, size_t ws_size,
                              hipStream_t stream) {
    const float* pos  = (const float*)d_in[0];
    const float* feat = (const float*)d_in[1];
    const int* hptr   = (const int*)d_in[2];
    const int* wptr   = (const int*)d_in[3];
    float* out        = (float*)d_out;

    const int N  = in_sizes[0] / 2;
    const int D  = in_sizes[1] / N;        // 112
    const int HW = out_size / D;           // H*W = 11264

    int* cnt  = (int*)d_ws;
    int* cur  = cnt + HW;
    int* off  = cur + HW;                  // HW+1 entries
    int* ep   = off + (HW + 1);
    float* ew = (float*)(ep + 4 * N);
    // required ws: (3*HW+1 + 8*N)*4 B ~= 16.2 MB

    hipMemsetAsync(cnt, 0, (size_t)HW * sizeof(int), stream);

    int blocks = (N + 255) / 256;
    count_kernel<<<blocks, 256, 0, stream>>>(pos, hptr, wptr, cnt, N);

    int K = (HW + 1023) / 1024;
    scan_kernel<<<1, 1024, 0, stream>>>(cnt, off, cur, HW, K);

    fill_kernel<<<blocks, 256, 0, stream>>>(pos, hptr, wptr, cur, ep, ew, N);

    accumulate_kernel<<<HW, 128, 0, stream>>>(feat, off, ep, ew, out, D);
}